// Round 10
// baseline (91.032 us; speedup 1.0000x reference)
//
#include <hip/hip_runtime.h>

// ---------------------------------------------------------------------------
// Conv2dfft == 3x3 SAME cross-correlation conv (pad=1) + bias.
// N=32, C=128, F=128, H=W=32.  Implicit-GEMM, bf16 MFMA 16x16x32.
// Round 17: af-RESIDENT LDS. R2/R16 showed main's cost is ~fixed per block
// and ~proportional to the 12-phase barrier/DMA cadence, not per-phase work.
// This kernel deletes the cadence: block owns an f-QUARTER (32 f), so ALL
// 12 weight groups fit LDS resident (73.7 KB), DMA'd once in the prologue.
// K-loop = 4 chunk-phases, 2 barriers each (single xs buffer swap); no
// in-loop DMA, no vm drains. Grid af traffic 75 -> 19 MB.
// Geometry: 256 blocks x 512 thr = (img 32 x h-half 2 x f-quarter 4),
// exactly 1 block/CU, 8 waves/CU (2/SIMD, same as the 84us kernels).
// Wave = 2 rows x 32 cols x 32 f: af reused 4x/read, bfr hoisted per-q ->
// 42 LDS reads / 72 MFMA (0.58 KB/MFMA, -22%). Inner loop q-major (p,q
// accumulation order swapped vs R15 -- absmax may shift in low bits).
// LDS total 122,688 B. bc2: [fq(4)][grp(12)][q(3)][fblk2(2)][lane(64)][8].
// ---------------------------------------------------------------------------

typedef short bf16x8 __attribute__((ext_vector_type(8)));   // 8 bf16 (4 VGPR)
typedef short bf16x4 __attribute__((ext_vector_type(4)));   // 4 bf16 (2 VGPR)
typedef float f32x4  __attribute__((ext_vector_type(4)));   // MFMA 16x16 acc

__device__ __forceinline__ short f2bf(float f) {            // RNE fp32->bf16
  unsigned u = __builtin_bit_cast(unsigned, f);
  u = (u + 0x7fffu + ((u >> 16) & 1u)) >> 16;
  return (short)u;
}

// global -> LDS async DMA, 16B per lane. LDS dest = wave-uniform base +
// lane*16 (HW-applied); global src is per-lane.
__device__ __forceinline__ void gload_lds16(const void* g, void* l) {
  using gptr_t = const __attribute__((address_space(1))) unsigned int*;
  using lptr_t = __attribute__((address_space(3))) unsigned int*;
  __builtin_amdgcn_global_load_lds((gptr_t)(unsigned long long)g,
                                   (lptr_t)(unsigned int)(unsigned long long)l,
                                   16, 0, 0);
}

// ---------------------------------------------------------------------------
// Prepass: weight (F,C,3,3) fp32 -> bf16 fragment-major, f-quarter major:
//   bc2[fq(4)][grp(12)][q(3)][fblk2(2)][lane(64)][j(8)]
// A-frag elem j of lane (quad*16+l15) = W[f=fq*32+fblk2*16+l15]
//                                        [c=chunk*32+quad*8+j], grp=chunk*3+p,
// tap = p*3+q. Per fq: 73,728 B contiguous (lane-linear within each group).
// ---------------------------------------------------------------------------
__global__ __launch_bounds__(256) void conv_wprep(const float* __restrict__ w,
                                                  short* __restrict__ bc2) {
  int tid = blockIdx.x * 256 + threadIdx.x;    // [0, 147456)
  float v = w[tid];                            // coalesced
  int f   = tid / 1152;                        // w layout: f*1152 + c*9 + tap
  int rem = tid - f * 1152;
  int c   = rem / 9;
  int tap = rem - c * 9;
  int p = tap / 3, q = tap - p * 3;
  int grp   = (c >> 5) * 3 + p;                // chunk*3 + p
  int fq    = f >> 5;
  int fblk2 = (f >> 4) & 1;
  int lane  = ((c >> 3) & 3) * 16 + (f & 15);  // quad*16 + l15
  int dst = ((((fq * 12 + grp) * 3 + q) * 2 + fblk2) * 512) + lane * 8 + (c & 7);
  bc2[dst] = f2bf(v);
}

// ---------------------------------------------------------------------------
// Main: 256 blocks (1/CU) x 512 threads (8 waves).
// Block b: n_img=b>>3, hhalf=(b>>2)&1 (rows h0=hhalf*16..+15), fq=b&3.
// Wave wv: output rows r_base=wv*2, r_base+1; 32 cols; 32 f.
// acc[row d(2)][mt(2)][nt(2)] of f32x4.
// ---------------------------------------------------------------------------
__global__ __launch_bounds__(512, 2) void conv_main(
    const float* __restrict__ x, const short* __restrict__ bc2,
    const float* __restrict__ bias, float* __restrict__ out) {
  // xs[row(18)][col(34)][c(32 + 8 pad)] ; stride 40 shorts = 80 B (proven
  // conflict-free). Single buffer, swapped with 2 barriers per chunk.
  __shared__ __align__(16) short xs[18 * 34 * 40];        // 48,960 B
  // afl[grp(12)][q(3)][fblk2(2)][lane(64)][8 shorts] -- ALL groups resident.
  __shared__ __align__(16) short afl[36864];              // 73,728 B

  const int t    = threadIdx.x;        // [0,512)
  const int lane = t & 63;
  const int wv   = t >> 6;             // [0,8)
  const int b     = blockIdx.x;
  const int n_img = b >> 3;            // [0,32)
  const int hhalf = (b >> 2) & 1;
  const int fq    = b & 3;
  const int h0    = hhalf << 4;        // {0,16}

  const int l15    = lane & 15;
  const int quad   = lane >> 4;
  const int f_off  = fq << 5;
  const int r_base = wv << 1;          // wave's output rows (within 16-row half)

  const int w_ = t & 31;               // staged output col (coalesced)
  const int g  = t >> 5;               // staging group [0,16)
  const float* xb = x + n_img * 128 * 1024;

  // ---- prologue: DMA the whole fq weight slice (73,728 B) into afl ----
  {
    const char* src = (const char*)bc2 + fq * 73728 + t * 16;
    char* dst = (char*)&afl[0] + wv * 1024;   // wave-uniform; HW adds lane*16
#pragma unroll
    for (int r = 0; r < 9; ++r)
      gload_lds16(src + r * 8192, dst + r * 8192);
  }

  // Zero halo cols (col 0 == w=-1, col 33 == w=32), 18 rows, once.
  // 18 r x 2 col x 8 int2 = 288 threads.
  if (t < 288) {
    int r = t >> 4, rem = t & 15;
    int colsel = rem >> 3, q4 = rem & 7;
    *(int2*)&xs[(r * 34 + colsel * 33) * 40 + q4 * 4] = make_int2(0, 0);
  }

  f32x4 acc[2][2][2] = {};             // [row d][mt][nt]
  float xv[36];

  // ---- chunk 0 x -> regs : rows h0-1..h0+16 (18), 32 c ----
#pragma unroll
  for (int i = 0; i < 9; ++i) {
    int idx = i * 16 + g;              // [0,144) = r*8 + cq
    int r = idx >> 3, cq = idx & 7;
    int hr = h0 - 1 + r;
    bool ok = (unsigned)hr < 32u;
#pragma unroll
    for (int cc = 0; cc < 4; ++cc)
      xv[i * 4 + cc] = ok ? xb[(cq * 4 + cc) * 1024 + hr * 32 + w_] : 0.f;
  }
#pragma unroll
  for (int i = 0; i < 9; ++i) {
    int idx = i * 16 + g;
    int r = idx >> 3, cq = idx & 7;
    bf16x4 v = { f2bf(xv[i*4+0]), f2bf(xv[i*4+1]), f2bf(xv[i*4+2]), f2bf(xv[i*4+3]) };
    *(bf16x4*)&xs[(r * 34 + w_ + 1) * 40 + cq * 4] = v;
  }
  __syncthreads();                     // af DMA drained + chunk-0 staged

#pragma unroll
  for (int chunk = 0; chunk < 4; ++chunk) {
    // ---- prefetch next chunk's x into regs (overlaps 72 MFMAs) ----
    if (chunk < 3) {
#pragma unroll
      for (int i = 0; i < 9; ++i) {
        int idx = i * 16 + g;
        int r = idx >> 3, cq = idx & 7;
        int hr = h0 - 1 + r;
        bool ok = (unsigned)hr < 32u;
#pragma unroll
        for (int cc = 0; cc < 4; ++cc)
          xv[i * 4 + cc] =
              ok ? xb[((chunk + 1) * 32 + cq * 4 + cc) * 1024 + hr * 32 + w_] : 0.f;
      }
    }
    // ---- compute: q-major, bfr hoisted (4 rows x 2 nt per q), 72 MFMA ----
    const int grp0 = chunk * 3;
#pragma unroll
    for (int q = 0; q < 3; ++q) {
      bf16x8 bfr[4][2];
#pragma unroll
      for (int rr = 0; rr < 4; ++rr)
#pragma unroll
        for (int nt = 0; nt < 2; ++nt)
          bfr[rr][nt] = *(const bf16x8*)
              &xs[((r_base + rr) * 34 + nt * 16 + l15 + q) * 40 + quad * 8];
#pragma unroll
      for (int p = 0; p < 3; ++p) {
        bf16x8 af0 = *(const bf16x8*)&afl[(((grp0 + p) * 3 + q) * 2 + 0) * 512 + lane * 8];
        bf16x8 af1 = *(const bf16x8*)&afl[(((grp0 + p) * 3 + q) * 2 + 1) * 512 + lane * 8];
#pragma unroll
        for (int d = 0; d < 2; ++d)
#pragma unroll
          for (int nt = 0; nt < 2; ++nt) {
            acc[d][0][nt] = __builtin_amdgcn_mfma_f32_16x16x32_bf16(
                af0, bfr[p + d][nt], acc[d][0][nt], 0, 0, 0);
            acc[d][1][nt] = __builtin_amdgcn_mfma_f32_16x16x32_bf16(
                af1, bfr[p + d][nt], acc[d][1][nt], 0, 0, 0);
          }
      }
    }
    // ---- swap xs: all reads done -> write next chunk -> visible ----
    if (chunk < 3) {
      __syncthreads();
#pragma unroll
      for (int i = 0; i < 9; ++i) {
        int idx = i * 16 + g;
        int r = idx >> 3, cq = idx & 7;
        bf16x4 v = { f2bf(xv[i*4+0]), f2bf(xv[i*4+1]), f2bf(xv[i*4+2]), f2bf(xv[i*4+3]) };
        *(bf16x4*)&xs[(r * 34 + w_ + 1) * 40 + cq * 4] = v;
      }
      __syncthreads();
    }
  }

  // ---- epilogue: C/D layout col=lane&15 (w), row=quad*4+reg (f) ----
#pragma unroll
  for (int d = 0; d < 2; ++d) {
    const int h = h0 + r_base + d;
#pragma unroll
    for (int nt = 0; nt < 2; ++nt) {
      int w_out = nt * 16 + l15;
#pragma unroll
      for (int mt = 0; mt < 2; ++mt) {
#pragma unroll
        for (int reg = 0; reg < 4; ++reg) {
          int f = f_off + mt * 16 + quad * 4 + reg;
          out[(((size_t)n_img * 128 + f) * 32 + h) * 32 + w_out] =
              acc[d][mt][nt][reg] + bias[f];
        }
      }
    }
  }
}

// ---------------------------------------------------------------------------
extern "C" void kernel_launch(void* const* d_in, const int* in_sizes, int n_in,
                              void* d_out, int out_size, void* d_ws, size_t ws_size,
                              hipStream_t stream) {
  const float* x    = (const float*)d_in[0];   // 32*128*32*32
  const float* w    = (const float*)d_in[1];   // 128*128*3*3
  const float* bias = (const float*)d_in[2];   // 128
  float* out = (float*)d_out;                  // 32*128*32*32
  short* bc2 = (short*)d_ws;                   // 294,912 B fragment-major weights

  conv_wprep<<<576, 256, 0, stream>>>(w, bc2);
  conv_main<<<256, 512, 0, stream>>>(x, bc2, bias, out);
}